// Round 4
// baseline (1536.890 us; speedup 1.0000x reference)
//
#include <hip/hip_runtime.h>
#include <hip/hip_bf16.h>
#include <cstddef>

// Problem constants
#define BATCH 32
#define TSTEPS 20
#define IN_DIM 3
#define WIDTH 256
#define HID 64
#define FC1_IN 327680   // HID * TSTEPS * WIDTH
#define FC1_OUT 512
#define OUT_DIM 3

typedef _Float16 half8 __attribute__((ext_vector_type(8)));
typedef float floatx4 __attribute__((ext_vector_type(4)));

__device__ __forceinline__ float sigm(float x) {
    return 1.0f / (1.0f + __expf(-x));
}
__device__ __forceinline__ float tanh_fast(float x) {
    return 1.0f - 2.0f / (__expf(2.0f * x) + 1.0f);
}

// ---------------- prep kernels (once per launch) ----------------

// wt0[kw][co][ci'=96]: ci' 0..2 = x ch, 3..7 = 0, 8..71 = h ch (orig 3..66), 72..95 = 0.
__global__ __launch_bounds__(256) void prep_w0(
    const float* __restrict__ cw0, _Float16* __restrict__ wt0)
{
    int e = blockIdx.x * 256 + threadIdx.x;   // < 256*96
    if (e >= 256 * 96) return;
    int co = e / 96, cip = e - co * 96;
    int ci = -1;
    if (cip < 3) ci = cip;
    else if (cip >= 8 && cip < 72) ci = cip - 5;
    float v[3] = {0.f, 0.f, 0.f};
    if (ci >= 0) {
#pragma unroll
        for (int kw = 0; kw < 3; ++kw)
            v[kw] = cw0[(size_t)(co * 67 + ci) * 9 + 3 + kw];
    }
#pragma unroll
    for (int kw = 0; kw < 3; ++kw)
        wt0[(size_t)(kw * 256 + co) * 96 + cip] = (_Float16)v[kw];
}

// wt1[kw][co][ci=128]: direct (z = [h0 64 | h1 64] matches cw1 ci order).
__global__ __launch_bounds__(256) void prep_w1(
    const float* __restrict__ cw1, _Float16* __restrict__ wt1)
{
    int e = blockIdx.x * 256 + threadIdx.x;   // < 256*128
    int co = e >> 7, ci = e & 127;
#pragma unroll
    for (int kw = 0; kw < 3; ++kw)
        wt1[(size_t)(kw * 256 + co) * 128 + ci] =
            (_Float16)cw1[(size_t)(co * 128 + ci) * 9 + 3 + kw];
}

// xT[t][b][w][8] fp16: ch 0..2 from x[b][t][ch][w], 3..7 = 0.
__global__ __launch_bounds__(256) void prep_x(
    const float* __restrict__ x, _Float16* __restrict__ xT)
{
    int e = blockIdx.x * 256 + threadIdx.x;   // < 20*32*256
    if (e >= TSTEPS * BATCH * WIDTH) return;
    int t = e / (BATCH * WIDTH);
    int rem = e - t * BATCH * WIDTH;
    int b = rem >> 8, w = rem & 255;
    half8 v = {};
#pragma unroll
    for (int ci = 0; ci < 3; ++ci)
        v[ci] = (_Float16)x[(size_t)((b * TSTEPS + t) * IN_DIM + ci) * WIDTH + w];
    *(half8*)&xT[(size_t)e * 8] = v;
}

// ---------------- persistent ConvLSTM: all 20 steps, both layers ----------------
// 256 blocks = (32 b) x (8 wtiles of 32 cols), 1 block/CU, 4 waves.
// State (h0,c0,h1,c1) lives in LDS. Layer0 computed on 34 cols (1-col redundant
// halo each side, bit-identical to neighbor's) so layer1 needs no intra-step sync.
// Cross-block halo (h0: 1 col/side, h1: 1 col/side) exchanged via parity-double-
// buffered global buffer + per-block step flags (release/acquire, agent scope).
__global__ __launch_bounds__(256, 1) void lstm_persistent(
    const _Float16* __restrict__ xT,
    const _Float16* __restrict__ wt0,
    const _Float16* __restrict__ wt1,
    const float* __restrict__ cb0,
    const float* __restrict__ cb1,
    _Float16* __restrict__ fcin,
    _Float16* __restrict__ ex,     // [256][2][4][64] fp16
    int* __restrict__ flags)       // [256], zeroed each launch
{
    __shared__ _Float16 z0h[50 * 128];   // 36 rows used, XOR-swizzled 16B slots
    __shared__ _Float16 z1h[34 * 128];
    __shared__ float glds[16 * 264];
    __shared__ _Float16 h0loc[34 * 64];  // col m <-> w0-1+m
    __shared__ float    c0loc[34 * 65];
    __shared__ _Float16 h1loc[32 * 64];  // col m <-> w0+m
    __shared__ float    c1loc[32 * 65];

    const int vb = blockIdx.x;
    const int b = vb & 31;          // vb%8 == b%8 -> all 8 wtiles of b on one XCD
    const int wtile = vb >> 5;
    const int w0 = wtile * 32;
    const int tid = threadIdx.x;
    const int g  = tid >> 6;        // wave = gate
    const int ln = tid & 63;
    const int lr = ln & 15;
    const int kg = ln >> 4;
    const int rr = tid >> 4;        // epilogue row
    const int q  = tid & 15;        // epilogue hc-group

    float cbr0[4][4], cbr1[4][4];
#pragma unroll
    for (int j = 0; j < 4; ++j) {
        int hc = q * 4 + j;
#pragma unroll
        for (int gg = 0; gg < 4; ++gg) {
            cbr0[gg][j] = cb0[gg * 64 + hc];
            cbr1[gg][j] = cb1[gg * 64 + hc];
        }
    }

    for (int i = tid; i < 50 * 128; i += 256) z0h[i] = (_Float16)0.0f;
    for (int i = tid; i < 34 * 64; i += 256) h0loc[i] = (_Float16)0.0f;
    for (int i = tid; i < 34 * 65; i += 256) c0loc[i] = 0.0f;
    for (int i = tid; i < 32 * 64; i += 256) h1loc[i] = (_Float16)0.0f;
    for (int i = tid; i < 32 * 65; i += 256) c1loc[i] = 0.0f;
    __syncthreads();

    for (int t = 0; t < TSTEPS; ++t) {
        const int pr = (t - 1) & 1;
        const bool haveL = (wtile > 0) && (t > 0);
        const bool haveR = (wtile < 7) && (t > 0);

        if (t > 0) {
            if (tid == 0) {
                if (wtile > 0)
                    while (__hip_atomic_load(&flags[vb - 32], __ATOMIC_ACQUIRE,
                                             __HIP_MEMORY_SCOPE_AGENT) < t)
                        __builtin_amdgcn_s_sleep(2);
                if (wtile < 7)
                    while (__hip_atomic_load(&flags[vb + 32], __ATOMIC_ACQUIRE,
                                             __HIP_MEMORY_SCOPE_AGENT) < t)
                        __builtin_amdgcn_s_sleep(2);
            }
            __syncthreads();
            __threadfence();
        }

        const _Float16* exLh0 = ex + (size_t)(((vb - 32) * 2 + pr) * 4 + 1) * 64;
        const _Float16* exLh1 = ex + (size_t)(((vb - 32) * 2 + pr) * 4 + 3) * 64;
        const _Float16* exRh0 = ex + (size_t)(((vb + 32) * 2 + pr) * 4 + 0) * 64;
        const _Float16* exRh1 = ex + (size_t)(((vb + 32) * 2 + pr) * 4 + 2) * 64;

        // ---- stage z0: rows j=0..35 (w = w0-2+j), chunks c: 0=x, 1..8=h0, 9..11=pad
        for (int i = tid; i < 36 * 12; i += 256) {
            int j = i / 12, c = i - j * 12;
            int wg = w0 - 2 + j;
            half8 v = {};
            if (wg >= 0 && wg < WIDTH) {
                if (c == 0) {
                    v = *(const half8*)&xT[(size_t)((t * BATCH + b) * WIDTH + wg) * 8];
                } else if (c <= 8) {
                    int ch = (c - 1) * 8;
                    if (j == 0)       { if (haveL) v = *(const half8*)&exLh0[ch]; }
                    else if (j == 35) { if (haveR) v = *(const half8*)&exRh0[ch]; }
                    else v = *(const half8*)&h0loc[(j - 1) * 64 + ch];
                }
            }
            int off = (j << 8) + ((c ^ (j & 7)) << 4);
            *(half8*)((char*)z0h + off) = v;
        }
        __syncthreads();

        // ---- layer0 MFMA: gates[n=0..33][256co], K = 3kw x 96
        floatx4 acc0[3][4];
#pragma unroll
        for (int nf = 0; nf < 3; ++nf)
#pragma unroll
            for (int cf = 0; cf < 4; ++cf) acc0[nf][cf] = (floatx4)0.0f;

#pragma unroll
        for (int kw = 0; kw < 3; ++kw)
#pragma unroll
        for (int kf = 0; kf < 3; ++kf) {
            half8 a[3];
#pragma unroll
            for (int nf = 0; nf < 3; ++nf) {
                int row = nf * 16 + lr + kw;
                int slot = kf * 4 + kg;
                int off = (row << 8) + ((slot ^ (row & 7)) << 4);
                a[nf] = *(const half8*)((const char*)z0h + off);
            }
#pragma unroll
            for (int cf = 0; cf < 4; ++cf) {
                half8 bf = *(const half8*)&wt0[
                    (size_t)(kw * 256 + g * 64 + cf * 16 + lr) * 96 + kf * 32 + kg * 8];
#pragma unroll
                for (int nf = 0; nf < 3; ++nf)
                    acc0[nf][cf] = __builtin_amdgcn_mfma_f32_16x16x32_f16(a[nf], bf, acc0[nf][cf], 0, 0, 0);
            }
        }

        // ---- layer0 epilogue, 3 chunks of 16 rows (rows >=34 discarded)
        for (int nf = 0; nf < 3; ++nf) {
            __syncthreads();
#pragma unroll
            for (int cf = 0; cf < 4; ++cf)
#pragma unroll
                for (int r = 0; r < 4; ++r)
                    glds[(kg * 4 + r) * 264 + g * 64 + cf * 16 + lr] = acc0[nf][cf][r];
            __syncthreads();
            int n = nf * 16 + rr;
            if (n < 34) {
                float4 gi = *(const float4*)&glds[rr * 264 + q * 4];
                float4 gf = *(const float4*)&glds[rr * 264 + 64 + q * 4];
                float4 go = *(const float4*)&glds[rr * 264 + 128 + q * 4];
                float4 gt = *(const float4*)&glds[rr * 264 + 192 + q * 4];
#pragma unroll
                for (int j = 0; j < 4; ++j) {
                    int hc = q * 4 + j;
                    float cv = c0loc[n * 65 + hc];
                    float cn = sigm((&gf.x)[j] + cbr0[1][j]) * cv
                             + sigm((&gi.x)[j] + cbr0[0][j]) * tanh_fast((&gt.x)[j] + cbr0[3][j]);
                    c0loc[n * 65 + hc] = cn;
                    h0loc[n * 64 + hc] = (_Float16)(sigm((&go.x)[j] + cbr0[2][j]) * tanh_fast(cn));
                }
            }
        }
        __syncthreads();

        // ---- stage z1: rows j=0..33 (w = w0-1+j), chunks 0..7=h0(this step), 8..15=h1prev
        for (int i = tid; i < 34 * 16; i += 256) {
            int j = i >> 4, c = i & 15;
            int wg = w0 - 1 + j;
            half8 v = {};
            if (wg >= 0 && wg < WIDTH) {
                if (c < 8) {
                    v = *(const half8*)&h0loc[j * 64 + c * 8];
                } else {
                    int ch = (c - 8) * 8;
                    if (j == 0)       { if (haveL) v = *(const half8*)&exLh1[ch]; }
                    else if (j == 33) { if (haveR) v = *(const half8*)&exRh1[ch]; }
                    else v = *(const half8*)&h1loc[(j - 1) * 64 + ch];
                }
            }
            int off = (j << 8) + ((c ^ (j & 7)) << 4);
            *(half8*)((char*)z1h + off) = v;
        }
        __syncthreads();

        // ---- layer1 MFMA: gates[n=0..31][256co], K = 3kw x 128
        floatx4 acc1[2][4];
#pragma unroll
        for (int nf = 0; nf < 2; ++nf)
#pragma unroll
            for (int cf = 0; cf < 4; ++cf) acc1[nf][cf] = (floatx4)0.0f;

#pragma unroll
        for (int kw = 0; kw < 3; ++kw)
#pragma unroll
        for (int kf = 0; kf < 4; ++kf) {
            half8 a[2];
#pragma unroll
            for (int nf = 0; nf < 2; ++nf) {
                int row = nf * 16 + lr + kw;
                int slot = kf * 4 + kg;
                int off = (row << 8) + ((slot ^ (row & 7)) << 4);
                a[nf] = *(const half8*)((const char*)z1h + off);
            }
#pragma unroll
            for (int cf = 0; cf < 4; ++cf) {
                half8 bf = *(const half8*)&wt1[
                    (size_t)(kw * 256 + g * 64 + cf * 16 + lr) * 128 + kf * 32 + kg * 8];
#pragma unroll
                for (int nf = 0; nf < 2; ++nf)
                    acc1[nf][cf] = __builtin_amdgcn_mfma_f32_16x16x32_f16(a[nf], bf, acc1[nf][cf], 0, 0, 0);
            }
        }

        // ---- layer1 epilogue, 2 chunks; writes fcin
        for (int nf = 0; nf < 2; ++nf) {
            __syncthreads();
#pragma unroll
            for (int cf = 0; cf < 4; ++cf)
#pragma unroll
                for (int r = 0; r < 4; ++r)
                    glds[(kg * 4 + r) * 264 + g * 64 + cf * 16 + lr] = acc1[nf][cf][r];
            __syncthreads();
            int n = nf * 16 + rr;
            {
                float4 gi = *(const float4*)&glds[rr * 264 + q * 4];
                float4 gf = *(const float4*)&glds[rr * 264 + 64 + q * 4];
                float4 go = *(const float4*)&glds[rr * 264 + 128 + q * 4];
                float4 gt = *(const float4*)&glds[rr * 264 + 192 + q * 4];
#pragma unroll
                for (int j = 0; j < 4; ++j) {
                    int hc = q * 4 + j;
                    float cv = c1loc[n * 65 + hc];
                    float cn = sigm((&gf.x)[j] + cbr1[1][j]) * cv
                             + sigm((&gi.x)[j] + cbr1[0][j]) * tanh_fast((&gt.x)[j] + cbr1[3][j]);
                    c1loc[n * 65 + hc] = cn;
                    _Float16 hv = (_Float16)(sigm((&go.x)[j] + cbr1[2][j]) * tanh_fast(cn));
                    h1loc[n * 64 + hc] = hv;
                    fcin[(size_t)((b * TSTEPS + t) * HID + hc) * WIDTH + (w0 + n)] = hv;
                }
            }
        }
        __syncthreads();

        // ---- publish halo edges + flag
        if (t < TSTEPS - 1) {
            int which = tid >> 6, ch = tid & 63;
            _Float16 v = (which == 0) ? h0loc[2 * 64 + ch]      // w0+1  -> left
                       : (which == 1) ? h0loc[31 * 64 + ch]     // w0+30 -> right
                       : (which == 2) ? h1loc[0 * 64 + ch]      // w0    -> left
                       :                h1loc[31 * 64 + ch];    // w0+31 -> right
            ex[(size_t)((vb * 2 + (t & 1)) * 4 + which) * 64 + ch] = v;
            __threadfence();
            __syncthreads();
            if (tid == 0)
                __hip_atomic_store(&flags[vb], t + 1, __ATOMIC_RELEASE,
                                   __HIP_MEMORY_SCOPE_AGENT);
        }
    }
}

// ---------------- FC1 fp16 MFMA GEMM, K-split ----------------
#define KSLICE 1280
#define KPHASE 640
#define ALDS_STRIDE 648

__global__ __launch_bounds__(512) void fc1_mfma(
    const _Float16* __restrict__ a,   // fcin [32][327680] fp16
    const float* __restrict__ w,      // fc1_w [512][327680] fp32
    float* __restrict__ part)         // [256][512][32] fp32 partials
{
    __shared__ _Float16 alds[32][ALDS_STRIDE];

    const int blk = blockIdx.x;
    const int tid = threadIdx.x;
    const int wv  = tid >> 6;
    const int ln  = tid & 63;
    const int lg  = ln >> 4;
    const int lr  = ln & 15;
    const int k0  = blk * KSLICE;

    floatx4 acc[2][4];
#pragma unroll
    for (int bt = 0; bt < 2; ++bt)
#pragma unroll
        for (int nt = 0; nt < 4; ++nt) acc[bt][nt] = (floatx4)0.0f;

    const float* wbase[4];
#pragma unroll
    for (int nt = 0; nt < 4; ++nt)
        wbase[nt] = w + (size_t)(wv * 64 + nt * 16 + lr) * FC1_IN + k0 + lg * 8;

    for (int p = 0; p < 2; ++p) {
        __syncthreads();
        for (int i = tid; i < 32 * 80; i += 512) {
            int r = i / 80;
            int c = (i - r * 80) * 8;
            *(half8*)&alds[r][c] =
                *(const half8*)&a[(size_t)r * FC1_IN + k0 + p * KPHASE + c];
        }
        __syncthreads();

        for (int kc = 0; kc < KPHASE / 32; ++kc) {
            half8 af0 = *(const half8*)&alds[lr][kc * 32 + lg * 8];
            half8 af1 = *(const half8*)&alds[16 + lr][kc * 32 + lg * 8];
#pragma unroll
            for (int nt = 0; nt < 4; ++nt) {
                const float* wp = wbase[nt] + p * KPHASE + kc * 32;
                float4 wlo = *(const float4*)wp;
                float4 whi = *(const float4*)(wp + 4);
                half8 bf;
                bf[0] = (_Float16)wlo.x; bf[1] = (_Float16)wlo.y;
                bf[2] = (_Float16)wlo.z; bf[3] = (_Float16)wlo.w;
                bf[4] = (_Float16)whi.x; bf[5] = (_Float16)whi.y;
                bf[6] = (_Float16)whi.z; bf[7] = (_Float16)whi.w;
                acc[0][nt] = __builtin_amdgcn_mfma_f32_16x16x32_f16(af0, bf, acc[0][nt], 0, 0, 0);
                acc[1][nt] = __builtin_amdgcn_mfma_f32_16x16x32_f16(af1, bf, acc[1][nt], 0, 0, 0);
            }
        }
    }

#pragma unroll
    for (int bt = 0; bt < 2; ++bt)
#pragma unroll
        for (int nt = 0; nt < 4; ++nt) {
            int n = wv * 64 + nt * 16 + lr;
            int b = bt * 16 + lg * 4;
            *(float4*)&part[((size_t)blk * FC1_OUT + n) * BATCH + b] =
                *(float4*)&acc[bt][nt];
        }
}

__global__ __launch_bounds__(256) void fc1_reduce(
    const float* __restrict__ part, const float* __restrict__ b1,
    float* __restrict__ z1)
{
    int e = blockIdx.x * 256 + threadIdx.x;  // e = n*32 + b
    float s = 0.0f;
    for (int ks = 0; ks < 256; ++ks)
        s += part[(size_t)ks * (FC1_OUT * BATCH) + e];
    int n = e >> 5, b = e & 31;
    float v = s + b1[n];
    z1[(size_t)b * FC1_OUT + n] = v > 0.0f ? v : 0.0f;
}

__global__ __launch_bounds__(128) void fc2_kernel(
    const float* __restrict__ z1, const float* __restrict__ w2,
    const float* __restrict__ b2, float* __restrict__ out)
{
    int t = threadIdx.x;
    if (t >= BATCH * OUT_DIM) return;
    int b = t / OUT_DIM, n = t - b * OUT_DIM;
    const float* zr = z1 + (size_t)b * FC1_OUT;
    const float* wr = w2 + (size_t)n * FC1_OUT;
    float acc = b2[n];
    for (int k = 0; k < FC1_OUT; ++k) acc += zr[k] * wr[k];
    if (n == 2) acc = sigm(acc);
    out[(size_t)b * OUT_DIM + n] = acc;
}

extern "C" void kernel_launch(void* const* d_in, const int* in_sizes, int n_in,
                              void* d_out, int out_size, void* d_ws, size_t ws_size,
                              hipStream_t stream) {
    const float* x   = (const float*)d_in[0];
    const float* cw0 = (const float*)d_in[1];
    const float* cb0 = (const float*)d_in[2];
    const float* cw1 = (const float*)d_in[3];
    const float* cb1 = (const float*)d_in[4];
    const float* w1  = (const float*)d_in[5];
    const float* b1  = (const float*)d_in[6];
    const float* w2  = (const float*)d_in[7];
    const float* b2  = (const float*)d_in[8];
    float* out = (float*)d_out;

    char* p = (char*)d_ws;
    auto alloc = [&](size_t bytes) { char* r = p; p += (bytes + 255) & ~(size_t)255; return r; };

    int*      flags = (int*)alloc(256 * sizeof(int));                 // zeroed every launch
    _Float16* ex    = (_Float16*)alloc((size_t)256 * 2 * 4 * 64 * 2);
    _Float16* wt0   = (_Float16*)alloc((size_t)3 * 256 * 96 * 2);
    _Float16* wt1   = (_Float16*)alloc((size_t)3 * 256 * 128 * 2);
    _Float16* xT    = (_Float16*)alloc((size_t)TSTEPS * BATCH * WIDTH * 8 * 2);
    _Float16* fcin  = (_Float16*)alloc((size_t)BATCH * FC1_IN * 2);
    float*    part  = (float*)alloc((size_t)256 * FC1_OUT * BATCH * 4);
    float*    z1    = (float*)alloc((size_t)BATCH * FC1_OUT * 4);

    hipMemsetAsync(flags, 0, 256 * sizeof(int), stream);  // captured -> re-zeroed per replay
    prep_w0<<<96, 256, 0, stream>>>(cw0, wt0);
    prep_w1<<<128, 256, 0, stream>>>(cw1, wt1);
    prep_x<<<(TSTEPS * BATCH * WIDTH + 255) / 256, 256, 0, stream>>>(x, xT);

    lstm_persistent<<<256, 256, 0, stream>>>(xT, wt0, wt1, cb0, cb1, fcin, ex, flags);

    fc1_mfma<<<256, 512, 0, stream>>>(fcin, w1, part);
    fc1_reduce<<<64, 256, 0, stream>>>(part, b1, z1);
    fc2_kernel<<<1, 128, 0, stream>>>(z1, w2, b2, out);
}

// Round 5
// 568.530 us; speedup vs baseline: 2.7033x; 2.7033x over previous
//
#include <hip/hip_runtime.h>
#include <hip/hip_bf16.h>
#include <cstddef>

// Problem constants
#define BATCH 32
#define TSTEPS 20
#define IN_DIM 3
#define WIDTH 256
#define HID 64
#define FC1_IN 327680   // HID * TSTEPS * WIDTH
#define FC1_OUT 512
#define OUT_DIM 3

typedef _Float16 half8 __attribute__((ext_vector_type(8)));
typedef _Float16 half4 __attribute__((ext_vector_type(4)));
typedef float floatx4 __attribute__((ext_vector_type(4)));

__device__ __forceinline__ float sigm(float x) {
    return 1.0f / (1.0f + __expf(-x));
}
__device__ __forceinline__ float tanh_fast(float x) {
    return 1.0f - 2.0f / (__expf(2.0f * x) + 1.0f);
}

// ---------------- prep kernels (once per launch) ----------------

// wt0[kw][co][ci'=96]: ci' 0..2 = x ch, 3..7 = 0, 8..71 = h ch (orig 3..66), 72..95 = 0.
__global__ __launch_bounds__(256) void prep_w0(
    const float* __restrict__ cw0, _Float16* __restrict__ wt0)
{
    int e = blockIdx.x * 256 + threadIdx.x;   // < 256*96
    if (e >= 256 * 96) return;
    int co = e / 96, cip = e - co * 96;
    int ci = -1;
    if (cip < 3) ci = cip;
    else if (cip >= 8 && cip < 72) ci = cip - 5;
    float v[3] = {0.f, 0.f, 0.f};
    if (ci >= 0) {
#pragma unroll
        for (int kw = 0; kw < 3; ++kw)
            v[kw] = cw0[(size_t)(co * 67 + ci) * 9 + 3 + kw];
    }
#pragma unroll
    for (int kw = 0; kw < 3; ++kw)
        wt0[(size_t)(kw * 256 + co) * 96 + cip] = (_Float16)v[kw];
}

// wt1[kw][co][ci=128]: direct (z = [h0 64 | h1 64] matches cw1 ci order).
__global__ __launch_bounds__(256) void prep_w1(
    const float* __restrict__ cw1, _Float16* __restrict__ wt1)
{
    int e = blockIdx.x * 256 + threadIdx.x;   // < 256*128
    int co = e >> 7, ci = e & 127;
#pragma unroll
    for (int kw = 0; kw < 3; ++kw)
        wt1[(size_t)(kw * 256 + co) * 128 + ci] =
            (_Float16)cw1[(size_t)(co * 128 + ci) * 9 + 3 + kw];
}

// xT[t][b][w][8] fp16: ch 0..2 from x[b][t][ch][w], 3..7 = 0.
__global__ __launch_bounds__(256) void prep_x(
    const float* __restrict__ x, _Float16* __restrict__ xT)
{
    int e = blockIdx.x * 256 + threadIdx.x;   // < 20*32*256
    if (e >= TSTEPS * BATCH * WIDTH) return;
    int t = e / (BATCH * WIDTH);
    int rem = e - t * BATCH * WIDTH;
    int b = rem >> 8, w = rem & 255;
    half8 v = {};
#pragma unroll
    for (int ci = 0; ci < 3; ++ci)
        v[ci] = (_Float16)x[(size_t)((b * TSTEPS + t) * IN_DIM + ci) * WIDTH + w];
    *(half8*)&xT[(size_t)e * 8] = v;
}

// ---------------- fused per-step kernel: layer0 + layer1 ----------------
// Grid (32 b, 8 wtiles of 32 cols), 256 threads = 4 waves; wave = gate.
// Layer0 computes 34 cols (1-col redundant halo each side, bit-identical to the
// neighbor's: identical MFMA K-order), passes h0 to layer1 via LDS (z1h). No
// inter-block sync needed inside a step; kernel boundary synchronizes steps.
// h0/c0/h1 ping-pong across steps (c0 halo reads race owner writes otherwise);
// c1 in place (owned cols only).
__global__ __launch_bounds__(256, 1) void conv2_step(
    const _Float16* __restrict__ xT,   // [t][b][w][8]
    const _Float16* __restrict__ wt0,  // [3][256][96]
    const _Float16* __restrict__ wt1,  // [3][256][128]
    const float* __restrict__ cb0,
    const float* __restrict__ cb1,
    const _Float16* __restrict__ h0p,  // [b][w][64] prev
    _Float16* __restrict__ h0n,
    const float* __restrict__ c0p,     // [b][w][64] prev
    float* __restrict__ c0n,
    const _Float16* __restrict__ h1p,
    _Float16* __restrict__ h1n,
    float* __restrict__ c1,            // in place
    _Float16* __restrict__ fcin,       // [b][t][hc][w] fp16
    int t)
{
    // z0h: rows j=0..49 (data rows 0..35, w = w0-2+j), 256B/row, XOR-swizzled
    // 16B chunks (chunk slot = c ^ (j&7)). Rows 36..49 are zero (A-loads for the
    // discarded tail rows of the nf=2 MFMA chunk read them).
    __shared__ __align__(16) _Float16 z0h[50 * 128];
    // z1h: rows j=0..33 (w = w0-1+j); chunks 0..7 = h0new (written by layer0
    // epilogue), 8..15 = h1prev (staged from global).
    __shared__ __align__(16) _Float16 z1h[34 * 128];
    __shared__ float glds[16 * 264];

    const int b     = blockIdx.x;
    const int wtile = blockIdx.y;
    const int w0    = wtile * 32;
    const int tid   = threadIdx.x;
    const int g  = tid >> 6;   // wave = gate (i,f,o,g)
    const int ln = tid & 63;
    const int lr = ln & 15;
    const int kg = ln >> 4;
    const int rr = tid >> 4;   // epilogue row-in-chunk
    const int q  = tid & 15;   // epilogue hc-group (4 hc each)

    float cbr0[4][4], cbr1[4][4];
#pragma unroll
    for (int j = 0; j < 4; ++j) {
        int hc = q * 4 + j;
#pragma unroll
        for (int gg = 0; gg < 4; ++gg) {
            cbr0[gg][j] = cb0[gg * 64 + hc];
            cbr1[gg][j] = cb1[gg * 64 + hc];
        }
    }

    // ---- stage z0 (chunks: 0=x, 1..8=h0prev, 9..11=pad) + zero tail rows
    for (int i = tid; i < 50 * 12; i += 256) {
        int j = i / 12, c = i - j * 12;
        int wg = w0 - 2 + j;
        half8 v = {};
        if (j < 36 && wg >= 0 && wg < WIDTH) {
            if (c == 0)
                v = *(const half8*)&xT[(size_t)((t * BATCH + b) * WIDTH + wg) * 8];
            else if (c <= 8)
                v = *(const half8*)&h0p[(size_t)(b * WIDTH + wg) * 64 + (c - 1) * 8];
        }
        int off = (j << 8) + ((c ^ (j & 7)) << 4);
        *(half8*)((char*)z0h + off) = v;
    }
    // ---- stage z1 chunks 8..15 = h1prev (rows j=0..33, w = w0-1+j)
    for (int i = tid; i < 34 * 8; i += 256) {
        int j = i >> 3, cc = i & 7;
        int wg = w0 - 1 + j;
        half8 v = {};
        if (wg >= 0 && wg < WIDTH)
            v = *(const half8*)&h1p[(size_t)(b * WIDTH + wg) * 64 + cc * 8];
        int c = cc + 8;
        int off = (j << 8) + ((c ^ (j & 7)) << 4);
        *(half8*)((char*)z1h + off) = v;
    }
    __syncthreads();

    // ---- layer0 MFMA: gates[n=0..33][256 co], K = 3kw x 96
    floatx4 acc0[3][4];
#pragma unroll
    for (int nf = 0; nf < 3; ++nf)
#pragma unroll
        for (int cf = 0; cf < 4; ++cf) acc0[nf][cf] = (floatx4)0.0f;

#pragma unroll
    for (int kw = 0; kw < 3; ++kw)
#pragma unroll
    for (int kf = 0; kf < 3; ++kf) {
        half8 a[3];
#pragma unroll
        for (int nf = 0; nf < 3; ++nf) {
            int row = nf * 16 + lr + kw;
            int slot = kf * 4 + kg;
            int off = (row << 8) + ((slot ^ (row & 7)) << 4);
            a[nf] = *(const half8*)((const char*)z0h + off);
        }
#pragma unroll
        for (int cf = 0; cf < 4; ++cf) {
            half8 bf = *(const half8*)&wt0[
                (size_t)(kw * 256 + g * 64 + cf * 16 + lr) * 96 + kf * 32 + kg * 8];
#pragma unroll
            for (int nf = 0; nf < 3; ++nf)
                acc0[nf][cf] = __builtin_amdgcn_mfma_f32_16x16x32_f16(a[nf], bf, acc0[nf][cf], 0, 0, 0);
        }
    }

    // ---- layer0 epilogue, 3 chunks of 16 rows (n >= 34 discarded)
    for (int nf = 0; nf < 3; ++nf) {
        __syncthreads();
#pragma unroll
        for (int cf = 0; cf < 4; ++cf)
#pragma unroll
            for (int r = 0; r < 4; ++r)
                glds[(kg * 4 + r) * 264 + g * 64 + cf * 16 + lr] = acc0[nf][cf][r];
        __syncthreads();
        int n = nf * 16 + rr;
        if (n < 34) {
            int w = w0 - 1 + n;
            bool wv = (w >= 0) && (w < WIDTH);
            float4 gi = *(const float4*)&glds[rr * 264 + q * 4];
            float4 gf = *(const float4*)&glds[rr * 264 + 64 + q * 4];
            float4 go = *(const float4*)&glds[rr * 264 + 128 + q * 4];
            float4 gt = *(const float4*)&glds[rr * 264 + 192 + q * 4];
            float4 cin = make_float4(0.f, 0.f, 0.f, 0.f);
            if (wv) cin = *(const float4*)&c0p[(size_t)(b * WIDTH + w) * 64 + q * 4];
            float cno[4];
            half4 hv = {};
            if (wv) {
#pragma unroll
                for (int j = 0; j < 4; ++j) {
                    float cn = sigm((&gf.x)[j] + cbr0[1][j]) * (&cin.x)[j]
                             + sigm((&gi.x)[j] + cbr0[0][j]) * tanh_fast((&gt.x)[j] + cbr0[3][j]);
                    cno[j] = cn;
                    hv[j] = (_Float16)(sigm((&go.x)[j] + cbr0[2][j]) * tanh_fast(cn));
                }
            }
            // h0new -> z1h chunks 0..7 (row n), zeros for invalid cols
            int zoff = (n << 8) + (((q >> 1) ^ (n & 7)) << 4) + (q & 1) * 8;
            *(half4*)((char*)z1h + zoff) = hv;
            if (n >= 1 && n <= 32) {  // owned cols -> global
                *(float4*)&c0n[(size_t)(b * WIDTH + w) * 64 + q * 4] = *(float4*)&cno[0];
                *(half4*)&h0n[(size_t)(b * WIDTH + w) * 64 + q * 4] = hv;
            }
        }
    }
    __syncthreads();

    // ---- layer1 MFMA: gates[n=0..31][256 co], K = 3kw x 128
    floatx4 acc1[2][4];
#pragma unroll
    for (int nf = 0; nf < 2; ++nf)
#pragma unroll
        for (int cf = 0; cf < 4; ++cf) acc1[nf][cf] = (floatx4)0.0f;

#pragma unroll
    for (int kw = 0; kw < 3; ++kw)
#pragma unroll
    for (int kf = 0; kf < 4; ++kf) {
        half8 a[2];
#pragma unroll
        for (int nf = 0; nf < 2; ++nf) {
            int row = nf * 16 + lr + kw;
            int slot = kf * 4 + kg;
            int off = (row << 8) + ((slot ^ (row & 7)) << 4);
            a[nf] = *(const half8*)((const char*)z1h + off);
        }
#pragma unroll
        for (int cf = 0; cf < 4; ++cf) {
            half8 bf = *(const half8*)&wt1[
                (size_t)(kw * 256 + g * 64 + cf * 16 + lr) * 128 + kf * 32 + kg * 8];
#pragma unroll
            for (int nf = 0; nf < 2; ++nf)
                acc1[nf][cf] = __builtin_amdgcn_mfma_f32_16x16x32_f16(a[nf], bf, acc1[nf][cf], 0, 0, 0);
        }
    }

    // ---- layer1 epilogue, 2 chunks; writes h1n, c1, fcin
    for (int nf = 0; nf < 2; ++nf) {
        __syncthreads();
#pragma unroll
        for (int cf = 0; cf < 4; ++cf)
#pragma unroll
            for (int r = 0; r < 4; ++r)
                glds[(kg * 4 + r) * 264 + g * 64 + cf * 16 + lr] = acc1[nf][cf][r];
        __syncthreads();
        int n = nf * 16 + rr;
        int w = w0 + n;
        float4 gi = *(const float4*)&glds[rr * 264 + q * 4];
        float4 gf = *(const float4*)&glds[rr * 264 + 64 + q * 4];
        float4 go = *(const float4*)&glds[rr * 264 + 128 + q * 4];
        float4 gt = *(const float4*)&glds[rr * 264 + 192 + q * 4];
        float4 cin = *(const float4*)&c1[(size_t)(b * WIDTH + w) * 64 + q * 4];
        float cno[4];
        half4 hv;
#pragma unroll
        for (int j = 0; j < 4; ++j) {
            float cn = sigm((&gf.x)[j] + cbr1[1][j]) * (&cin.x)[j]
                     + sigm((&gi.x)[j] + cbr1[0][j]) * tanh_fast((&gt.x)[j] + cbr1[3][j]);
            cno[j] = cn;
            hv[j] = (_Float16)(sigm((&go.x)[j] + cbr1[2][j]) * tanh_fast(cn));
        }
        *(float4*)&c1[(size_t)(b * WIDTH + w) * 64 + q * 4] = *(float4*)&cno[0];
        *(half4*)&h1n[(size_t)(b * WIDTH + w) * 64 + q * 4] = hv;
#pragma unroll
        for (int j = 0; j < 4; ++j)
            fcin[(size_t)((b * TSTEPS + t) * HID + q * 4 + j) * WIDTH + w] = hv[j];
    }
}

// ---------------- FC1 fp16 MFMA GEMM, K-split ----------------
#define KSLICE 1280
#define KPHASE 640
#define ALDS_STRIDE 648

__global__ __launch_bounds__(512) void fc1_mfma(
    const _Float16* __restrict__ a,   // fcin [32][327680] fp16
    const float* __restrict__ w,      // fc1_w [512][327680] fp32
    float* __restrict__ part)         // [256][512][32] fp32 partials
{
    __shared__ _Float16 alds[32][ALDS_STRIDE];

    const int blk = blockIdx.x;
    const int tid = threadIdx.x;
    const int wv  = tid >> 6;
    const int ln  = tid & 63;
    const int lg  = ln >> 4;
    const int lr  = ln & 15;
    const int k0  = blk * KSLICE;

    floatx4 acc[2][4];
#pragma unroll
    for (int bt = 0; bt < 2; ++bt)
#pragma unroll
        for (int nt = 0; nt < 4; ++nt) acc[bt][nt] = (floatx4)0.0f;

    const float* wbase[4];
#pragma unroll
    for (int nt = 0; nt < 4; ++nt)
        wbase[nt] = w + (size_t)(wv * 64 + nt * 16 + lr) * FC1_IN + k0 + lg * 8;

    for (int p = 0; p < 2; ++p) {
        __syncthreads();
        for (int i = tid; i < 32 * 80; i += 512) {
            int r = i / 80;
            int c = (i - r * 80) * 8;
            *(half8*)&alds[r][c] =
                *(const half8*)&a[(size_t)r * FC1_IN + k0 + p * KPHASE + c];
        }
        __syncthreads();

        for (int kc = 0; kc < KPHASE / 32; ++kc) {
            half8 af0 = *(const half8*)&alds[lr][kc * 32 + lg * 8];
            half8 af1 = *(const half8*)&alds[16 + lr][kc * 32 + lg * 8];
#pragma unroll
            for (int nt = 0; nt < 4; ++nt) {
                const float* wp = wbase[nt] + p * KPHASE + kc * 32;
                float4 wlo = *(const float4*)wp;
                float4 whi = *(const float4*)(wp + 4);
                half8 bf;
                bf[0] = (_Float16)wlo.x; bf[1] = (_Float16)wlo.y;
                bf[2] = (_Float16)wlo.z; bf[3] = (_Float16)wlo.w;
                bf[4] = (_Float16)whi.x; bf[5] = (_Float16)whi.y;
                bf[6] = (_Float16)whi.z; bf[7] = (_Float16)whi.w;
                acc[0][nt] = __builtin_amdgcn_mfma_f32_16x16x32_f16(af0, bf, acc[0][nt], 0, 0, 0);
                acc[1][nt] = __builtin_amdgcn_mfma_f32_16x16x32_f16(af1, bf, acc[1][nt], 0, 0, 0);
            }
        }
    }

#pragma unroll
    for (int bt = 0; bt < 2; ++bt)
#pragma unroll
        for (int nt = 0; nt < 4; ++nt) {
            int n = wv * 64 + nt * 16 + lr;
            int b = bt * 16 + lg * 4;
            *(float4*)&part[((size_t)blk * FC1_OUT + n) * BATCH + b] =
                *(float4*)&acc[bt][nt];
        }
}

__global__ __launch_bounds__(256) void fc1_reduce(
    const float* __restrict__ part, const float* __restrict__ b1,
    float* __restrict__ z1)
{
    int e = blockIdx.x * 256 + threadIdx.x;  // e = n*32 + b
    float s = 0.0f;
    for (int ks = 0; ks < 256; ++ks)
        s += part[(size_t)ks * (FC1_OUT * BATCH) + e];
    int n = e >> 5, b = e & 31;
    float v = s + b1[n];
    z1[(size_t)b * FC1_OUT + n] = v > 0.0f ? v : 0.0f;
}

__global__ __launch_bounds__(128) void fc2_kernel(
    const float* __restrict__ z1, const float* __restrict__ w2,
    const float* __restrict__ b2, float* __restrict__ out)
{
    int t = threadIdx.x;
    if (t >= BATCH * OUT_DIM) return;
    int b = t / OUT_DIM, n = t - b * OUT_DIM;
    const float* zr = z1 + (size_t)b * FC1_OUT;
    const float* wr = w2 + (size_t)n * FC1_OUT;
    float acc = b2[n];
    for (int k = 0; k < FC1_OUT; ++k) acc += zr[k] * wr[k];
    if (n == 2) acc = sigm(acc);
    out[(size_t)b * OUT_DIM + n] = acc;
}

extern "C" void kernel_launch(void* const* d_in, const int* in_sizes, int n_in,
                              void* d_out, int out_size, void* d_ws, size_t ws_size,
                              hipStream_t stream) {
    const float* x   = (const float*)d_in[0];
    const float* cw0 = (const float*)d_in[1];
    const float* cb0 = (const float*)d_in[2];
    const float* cw1 = (const float*)d_in[3];
    const float* cb1 = (const float*)d_in[4];
    const float* w1  = (const float*)d_in[5];
    const float* b1  = (const float*)d_in[6];
    const float* w2  = (const float*)d_in[7];
    const float* b2  = (const float*)d_in[8];
    float* out = (float*)d_out;

    const size_t S = (size_t)BATCH * WIDTH * HID;   // 524288 elements
    char* p = (char*)d_ws;
    auto alloc = [&](size_t bytes) { char* r = p; p += (bytes + 255) & ~(size_t)255; return r; };

    // zero block first (read at t=0): h0a, h1a, c0a, c1
    _Float16* h0a = (_Float16*)alloc(S * 2);
    _Float16* h1a = (_Float16*)alloc(S * 2);
    float*    c0a = (float*)alloc(S * 4);
    float*    c1  = (float*)alloc(S * 4);
    size_t zero_bytes = (size_t)(p - (char*)d_ws);

    _Float16* h0b = (_Float16*)alloc(S * 2);
    _Float16* h1b = (_Float16*)alloc(S * 2);
    float*    c0b = (float*)alloc(S * 4);
    _Float16* wt0 = (_Float16*)alloc((size_t)3 * 256 * 96 * 2);
    _Float16* wt1 = (_Float16*)alloc((size_t)3 * 256 * 128 * 2);
    _Float16* xT  = (_Float16*)alloc((size_t)TSTEPS * BATCH * WIDTH * 8 * 2);
    _Float16* fcin = (_Float16*)alloc((size_t)BATCH * FC1_IN * 2);
    float* part = (float*)alloc((size_t)256 * FC1_OUT * BATCH * 4);
    float* z1   = (float*)alloc((size_t)BATCH * FC1_OUT * 4);

    hipMemsetAsync(d_ws, 0, zero_bytes, stream);
    prep_w0<<<96, 256, 0, stream>>>(cw0, wt0);
    prep_w1<<<128, 256, 0, stream>>>(cw1, wt1);
    prep_x<<<(TSTEPS * BATCH * WIDTH + 255) / 256, 256, 0, stream>>>(x, xT);

    dim3 cgrid(BATCH, 8);
    for (int t = 0; t < TSTEPS; ++t) {
        const _Float16* h0r = (t & 1) ? h0b : h0a;
        _Float16*       h0w = (t & 1) ? h0a : h0b;
        const float*    c0r = (t & 1) ? c0b : c0a;
        float*          c0w = (t & 1) ? c0a : c0b;
        const _Float16* h1r = (t & 1) ? h1b : h1a;
        _Float16*       h1w = (t & 1) ? h1a : h1b;
        conv2_step<<<cgrid, 256, 0, stream>>>(
            xT, wt0, wt1, cb0, cb1,
            h0r, h0w, c0r, c0w, h1r, h1w, c1, fcin, t);
    }

    fc1_mfma<<<256, 512, 0, stream>>>(fcin, w1, part);
    fc1_reduce<<<64, 256, 0, stream>>>(part, b1, z1);
    fc2_kernel<<<1, 128, 0, stream>>>(z1, w2, b2, out);
}

// Round 6
// 553.120 us; speedup vs baseline: 2.7786x; 1.0279x over previous
//
#include <hip/hip_runtime.h>
#include <hip/hip_bf16.h>
#include <cstddef>

// Problem constants
#define BATCH 32
#define TSTEPS 20
#define IN_DIM 3
#define WIDTH 256
#define HID 64
#define FC1_IN 327680   // HID * TSTEPS * WIDTH
#define FC1_OUT 512
#define OUT_DIM 3

typedef _Float16 half8 __attribute__((ext_vector_type(8)));
typedef _Float16 half4 __attribute__((ext_vector_type(4)));
typedef float floatx4 __attribute__((ext_vector_type(4)));

__device__ __forceinline__ float sigm(float x) {
    return 1.0f / (1.0f + __expf(-x));
}
__device__ __forceinline__ float tanh_fast(float x) {
    return 1.0f - 2.0f / (__expf(2.0f * x) + 1.0f);
}

// ---------------- prep kernels (once per launch) ----------------

// wt0[kw][co][ci'=96]: ci' 0..2 = x ch, 3..7 = 0, 8..71 = h ch (orig 3..66), 72..95 = 0.
__global__ __launch_bounds__(256) void prep_w0(
    const float* __restrict__ cw0, _Float16* __restrict__ wt0)
{
    int e = blockIdx.x * 256 + threadIdx.x;   // < 256*96
    if (e >= 256 * 96) return;
    int co = e / 96, cip = e - co * 96;
    int ci = -1;
    if (cip < 3) ci = cip;
    else if (cip >= 8 && cip < 72) ci = cip - 5;
    float v[3] = {0.f, 0.f, 0.f};
    if (ci >= 0) {
#pragma unroll
        for (int kw = 0; kw < 3; ++kw)
            v[kw] = cw0[(size_t)(co * 67 + ci) * 9 + 3 + kw];
    }
#pragma unroll
    for (int kw = 0; kw < 3; ++kw)
        wt0[(size_t)(kw * 256 + co) * 96 + cip] = (_Float16)v[kw];
}

// wt1[kw][co][ci=128]: direct (z = [h0 64 | h1 64] matches cw1 ci order).
__global__ __launch_bounds__(256) void prep_w1(
    const float* __restrict__ cw1, _Float16* __restrict__ wt1)
{
    int e = blockIdx.x * 256 + threadIdx.x;   // < 256*128
    int co = e >> 7, ci = e & 127;
#pragma unroll
    for (int kw = 0; kw < 3; ++kw)
        wt1[(size_t)(kw * 256 + co) * 128 + ci] =
            (_Float16)cw1[(size_t)(co * 128 + ci) * 9 + 3 + kw];
}

// xT[t][b][w][8] fp16: ch 0..2 from x[b][t][ch][w], 3..7 = 0.
__global__ __launch_bounds__(256) void prep_x(
    const float* __restrict__ x, _Float16* __restrict__ xT)
{
    int e = blockIdx.x * 256 + threadIdx.x;   // < 20*32*256
    if (e >= TSTEPS * BATCH * WIDTH) return;
    int t = e / (BATCH * WIDTH);
    int rem = e - t * BATCH * WIDTH;
    int b = rem >> 8, w = rem & 255;
    half8 v = {};
#pragma unroll
    for (int ci = 0; ci < 3; ++ci)
        v[ci] = (_Float16)x[(size_t)((b * TSTEPS + t) * IN_DIM + ci) * WIDTH + w];
    *(half8*)&xT[(size_t)e * 8] = v;
}

// ---------------- fused per-step kernel: layer0 + layer1 ----------------
// Grid (32 b, 8 wtiles of 32 cols), 256 threads = 4 waves.
// Wave wv owns hc-slice [wv*16, wv*16+16) and computes ALL 4 gates for it
// (MFMA col tiles co = cf*64 + wv*16, cf = gate index) -> the LSTM epilogue is
// register-local per thread: no gate transpose through LDS, only 2 barriers.
// Layer0 computes 34 cols (1-col redundant halo each side, bit-identical to the
// neighbor's: identical MFMA K-order); h0 goes to layer1 via LDS (z1h).
// h0/c0/h1 ping-pong across steps; c1 in place (owned cols only).
__global__ __launch_bounds__(256) void conv2_step(
    const _Float16* __restrict__ xT,   // [t][b][w][8]
    const _Float16* __restrict__ wt0,  // [3][256][96]
    const _Float16* __restrict__ wt1,  // [3][256][128]
    const float* __restrict__ cb0,
    const float* __restrict__ cb1,
    const _Float16* __restrict__ h0p,  // [b][w][64] prev
    _Float16* __restrict__ h0n,
    const float* __restrict__ c0p,     // [b][w][64] prev
    float* __restrict__ c0n,
    const _Float16* __restrict__ h1p,
    _Float16* __restrict__ h1n,
    float* __restrict__ c1,            // in place
    _Float16* __restrict__ fcin,       // [b][(t*64+hc)*256+w] fp16
    int t)
{
    // z0h: rows j=0..49 (data rows 0..35, w = w0-2+j), 256B/row, XOR-swizzled
    // 16B chunks (slot = c ^ (j&7)). Rows 36..49 zero (A-tail of nf=2 chunk).
    __shared__ __align__(16) _Float16 z0h[50 * 128];
    // z1h: rows j=0..33 (w = w0-1+j); chunks 0..7 = h0new (epilogue scalar
    // writes), 8..15 = h1prev (staged).
    __shared__ __align__(16) _Float16 z1h[34 * 128];

    const int b     = blockIdx.x;
    const int wtile = blockIdx.y;
    const int w0    = wtile * 32;
    const int tid   = threadIdx.x;
    const int wv = tid >> 6;   // wave = hc-slice
    const int ln = tid & 63;
    const int lr = ln & 15;
    const int kg = ln >> 4;
    const int hc = wv * 16 + lr;

    float cbr0[4], cbr1[4];
#pragma unroll
    for (int cf = 0; cf < 4; ++cf) {
        cbr0[cf] = cb0[cf * 64 + hc];
        cbr1[cf] = cb1[cf * 64 + hc];
    }

    // ---- stage z0 (chunks: 0=x, 1..8=h0prev, 9..11=pad) + zero tail rows
    for (int i = tid; i < 50 * 12; i += 256) {
        int j = i / 12, c = i - j * 12;
        int wg = w0 - 2 + j;
        half8 v = {};
        if (j < 36 && wg >= 0 && wg < WIDTH) {
            if (c == 0)
                v = *(const half8*)&xT[(size_t)((t * BATCH + b) * WIDTH + wg) * 8];
            else if (c <= 8)
                v = *(const half8*)&h0p[(size_t)(b * WIDTH + wg) * 64 + (c - 1) * 8];
        }
        int off = (j << 8) + ((c ^ (j & 7)) << 4);
        *(half8*)((char*)z0h + off) = v;
    }
    // ---- stage z1 chunks 8..15 = h1prev (rows j=0..33, w = w0-1+j)
    for (int i = tid; i < 34 * 8; i += 256) {
        int j = i >> 3, cc = i & 7;
        int wg = w0 - 1 + j;
        half8 v = {};
        if (wg >= 0 && wg < WIDTH)
            v = *(const half8*)&h1p[(size_t)(b * WIDTH + wg) * 64 + cc * 8];
        int c = cc + 8;
        int off = (j << 8) + ((c ^ (j & 7)) << 4);
        *(half8*)((char*)z1h + off) = v;
    }
    __syncthreads();

    // ---- layer0 MFMA: gates[n=0..33][co], K = 3kw x 96; this wave: co = cf*64 + hc
    floatx4 acc0[3][4];
#pragma unroll
    for (int nf = 0; nf < 3; ++nf)
#pragma unroll
        for (int cf = 0; cf < 4; ++cf) acc0[nf][cf] = (floatx4)0.0f;

#pragma unroll
    for (int kw = 0; kw < 3; ++kw)
#pragma unroll
    for (int kf = 0; kf < 3; ++kf) {
        half8 a[3];
#pragma unroll
        for (int nf = 0; nf < 3; ++nf) {
            int row = nf * 16 + lr + kw;
            int slot = (kf * 4 + kg) ^ (row & 7);
            a[nf] = *(const half8*)((const char*)z0h + (row << 8) + (slot << 4));
        }
#pragma unroll
        for (int cf = 0; cf < 4; ++cf) {
            half8 bf = *(const half8*)&wt0[
                (size_t)(kw * 256 + cf * 64 + hc) * 96 + kf * 32 + kg * 8];
#pragma unroll
            for (int nf = 0; nf < 3; ++nf)
                acc0[nf][cf] = __builtin_amdgcn_mfma_f32_16x16x32_f16(a[nf], bf, acc0[nf][cf], 0, 0, 0);
        }
    }

    // ---- layer0 epilogue: register-local (thread owns n = nf*16+kg*4+r, this hc)
#pragma unroll
    for (int nf = 0; nf < 3; ++nf)
#pragma unroll
    for (int r = 0; r < 4; ++r) {
        int n = nf * 16 + kg * 4 + r;
        if (n >= 34) continue;
        int w = w0 - 1 + n;
        bool valid = (w >= 0) && (w < WIDTH);
        _Float16 hv = (_Float16)0.0f;
        if (valid) {
            size_t idx = (size_t)(b * WIDTH + w) * 64 + hc;
            float cin = c0p[idx];
            float cn = sigm(acc0[nf][1][r] + cbr0[1]) * cin
                     + sigm(acc0[nf][0][r] + cbr0[0]) * tanh_fast(acc0[nf][3][r] + cbr0[3]);
            hv = (_Float16)(sigm(acc0[nf][2][r] + cbr0[2]) * tanh_fast(cn));
            if (n >= 1 && n <= 32) {
                c0n[idx] = cn;
                h0n[idx] = hv;
            }
        }
        int c = hc >> 3;
        int off = (n << 8) + (((c ^ (n & 7))) << 4) + (hc & 7) * 2;
        *(_Float16*)((char*)z1h + off) = hv;
    }
    __syncthreads();

    // ---- layer1 MFMA: gates[n=0..31][co], K = 3kw x 128
    floatx4 acc1[2][4];
#pragma unroll
    for (int nf = 0; nf < 2; ++nf)
#pragma unroll
        for (int cf = 0; cf < 4; ++cf) acc1[nf][cf] = (floatx4)0.0f;

#pragma unroll
    for (int kw = 0; kw < 3; ++kw)
#pragma unroll
    for (int kf = 0; kf < 4; ++kf) {
        half8 a[2];
#pragma unroll
        for (int nf = 0; nf < 2; ++nf) {
            int row = nf * 16 + lr + kw;
            int slot = (kf * 4 + kg) ^ (row & 7);
            a[nf] = *(const half8*)((const char*)z1h + (row << 8) + (slot << 4));
        }
#pragma unroll
        for (int cf = 0; cf < 4; ++cf) {
            half8 bf = *(const half8*)&wt1[
                (size_t)(kw * 256 + cf * 64 + hc) * 128 + kf * 32 + kg * 8];
#pragma unroll
            for (int nf = 0; nf < 2; ++nf)
                acc1[nf][cf] = __builtin_amdgcn_mfma_f32_16x16x32_f16(a[nf], bf, acc1[nf][cf], 0, 0, 0);
        }
    }

    // ---- layer1 epilogue: register-local; writes h1n, c1, fcin
#pragma unroll
    for (int nf = 0; nf < 2; ++nf)
#pragma unroll
    for (int r = 0; r < 4; ++r) {
        int n = nf * 16 + kg * 4 + r;
        int w = w0 + n;
        size_t idx = (size_t)(b * WIDTH + w) * 64 + hc;
        float cin = c1[idx];
        float cn = sigm(acc1[nf][1][r] + cbr1[1]) * cin
                 + sigm(acc1[nf][0][r] + cbr1[0]) * tanh_fast(acc1[nf][3][r] + cbr1[3]);
        _Float16 hv = (_Float16)(sigm(acc1[nf][2][r] + cbr1[2]) * tanh_fast(cn));
        c1[idx] = cn;
        h1n[idx] = hv;
        fcin[(size_t)b * FC1_IN + (size_t)(t * HID + hc) * WIDTH + w] = hv;
    }
}

// ---------------- FC1 fp16 MFMA GEMM, K-split ----------------
#define KSLICE 1280
#define KPHASE 640
#define ALDS_STRIDE 648

__global__ __launch_bounds__(512) void fc1_mfma(
    const _Float16* __restrict__ a,   // fcin [32][327680] fp16
    const float* __restrict__ w,      // fc1_w [512][327680] fp32
    float* __restrict__ part)         // [256][512][32] fp32 partials
{
    __shared__ _Float16 alds[32][ALDS_STRIDE];

    const int blk = blockIdx.x;
    const int tid = threadIdx.x;
    const int wv  = tid >> 6;
    const int ln  = tid & 63;
    const int lg  = ln >> 4;
    const int lr  = ln & 15;
    const int k0  = blk * KSLICE;

    floatx4 acc[2][4];
#pragma unroll
    for (int bt = 0; bt < 2; ++bt)
#pragma unroll
        for (int nt = 0; nt < 4; ++nt) acc[bt][nt] = (floatx4)0.0f;

    const float* wbase[4];
#pragma unroll
    for (int nt = 0; nt < 4; ++nt)
        wbase[nt] = w + (size_t)(wv * 64 + nt * 16 + lr) * FC1_IN + k0 + lg * 8;

    for (int p = 0; p < 2; ++p) {
        __syncthreads();
        for (int i = tid; i < 32 * 80; i += 512) {
            int r = i / 80;
            int c = (i - r * 80) * 8;
            *(half8*)&alds[r][c] =
                *(const half8*)&a[(size_t)r * FC1_IN + k0 + p * KPHASE + c];
        }
        __syncthreads();

        for (int kc = 0; kc < KPHASE / 32; ++kc) {
            half8 af0 = *(const half8*)&alds[lr][kc * 32 + lg * 8];
            half8 af1 = *(const half8*)&alds[16 + lr][kc * 32 + lg * 8];
#pragma unroll
            for (int nt = 0; nt < 4; ++nt) {
                const float* wp = wbase[nt] + p * KPHASE + kc * 32;
                float4 wlo = *(const float4*)wp;
                float4 whi = *(const float4*)(wp + 4);
                half8 bf;
                bf[0] = (_Float16)wlo.x; bf[1] = (_Float16)wlo.y;
                bf[2] = (_Float16)wlo.z; bf[3] = (_Float16)wlo.w;
                bf[4] = (_Float16)whi.x; bf[5] = (_Float16)whi.y;
                bf[6] = (_Float16)whi.z; bf[7] = (_Float16)whi.w;
                acc[0][nt] = __builtin_amdgcn_mfma_f32_16x16x32_f16(af0, bf, acc[0][nt], 0, 0, 0);
                acc[1][nt] = __builtin_amdgcn_mfma_f32_16x16x32_f16(af1, bf, acc[1][nt], 0, 0, 0);
            }
        }
    }

#pragma unroll
    for (int bt = 0; bt < 2; ++bt)
#pragma unroll
        for (int nt = 0; nt < 4; ++nt) {
            int n = wv * 64 + nt * 16 + lr;
            int b = bt * 16 + lg * 4;
            *(float4*)&part[((size_t)blk * FC1_OUT + n) * BATCH + b] =
                *(float4*)&acc[bt][nt];
        }
}

__global__ __launch_bounds__(256) void fc1_reduce(
    const float* __restrict__ part, const float* __restrict__ b1,
    float* __restrict__ z1)
{
    int e = blockIdx.x * 256 + threadIdx.x;  // e = n*32 + b
    float s = 0.0f;
    for (int ks = 0; ks < 256; ++ks)
        s += part[(size_t)ks * (FC1_OUT * BATCH) + e];
    int n = e >> 5, b = e & 31;
    float v = s + b1[n];
    z1[(size_t)b * FC1_OUT + n] = v > 0.0f ? v : 0.0f;
}

__global__ __launch_bounds__(128) void fc2_kernel(
    const float* __restrict__ z1, const float* __restrict__ w2,
    const float* __restrict__ b2, float* __restrict__ out)
{
    int t = threadIdx.x;
    if (t >= BATCH * OUT_DIM) return;
    int b = t / OUT_DIM, n = t - b * OUT_DIM;
    const float* zr = z1 + (size_t)b * FC1_OUT;
    const float* wr = w2 + (size_t)n * FC1_OUT;
    float acc = b2[n];
    for (int k = 0; k < FC1_OUT; ++k) acc += zr[k] * wr[k];
    if (n == 2) acc = sigm(acc);
    out[(size_t)b * OUT_DIM + n] = acc;
}

extern "C" void kernel_launch(void* const* d_in, const int* in_sizes, int n_in,
                              void* d_out, int out_size, void* d_ws, size_t ws_size,
                              hipStream_t stream) {
    const float* x   = (const float*)d_in[0];
    const float* cw0 = (const float*)d_in[1];
    const float* cb0 = (const float*)d_in[2];
    const float* cw1 = (const float*)d_in[3];
    const float* cb1 = (const float*)d_in[4];
    const float* w1  = (const float*)d_in[5];
    const float* b1  = (const float*)d_in[6];
    const float* w2  = (const float*)d_in[7];
    const float* b2  = (const float*)d_in[8];
    float* out = (float*)d_out;

    const size_t S = (size_t)BATCH * WIDTH * HID;   // 524288 elements
    char* p = (char*)d_ws;
    auto alloc = [&](size_t bytes) { char* r = p; p += (bytes + 255) & ~(size_t)255; return r; };

    // zero block first (read at t=0): h0a, h1a, c0a, c1
    _Float16* h0a = (_Float16*)alloc(S * 2);
    _Float16* h1a = (_Float16*)alloc(S * 2);
    float*    c0a = (float*)alloc(S * 4);
    float*    c1  = (float*)alloc(S * 4);
    size_t zero_bytes = (size_t)(p - (char*)d_ws);

    _Float16* h0b = (_Float16*)alloc(S * 2);
    _Float16* h1b = (_Float16*)alloc(S * 2);
    float*    c0b = (float*)alloc(S * 4);
    _Float16* wt0 = (_Float16*)alloc((size_t)3 * 256 * 96 * 2);
    _Float16* wt1 = (_Float16*)alloc((size_t)3 * 256 * 128 * 2);
    _Float16* xT  = (_Float16*)alloc((size_t)TSTEPS * BATCH * WIDTH * 8 * 2);
    _Float16* fcin = (_Float16*)alloc((size_t)BATCH * FC1_IN * 2);
    float* part = (float*)alloc((size_t)256 * FC1_OUT * BATCH * 4);
    float* z1   = (float*)alloc((size_t)BATCH * FC1_OUT * 4);

    hipMemsetAsync(d_ws, 0, zero_bytes, stream);
    prep_w0<<<96, 256, 0, stream>>>(cw0, wt0);
    prep_w1<<<128, 256, 0, stream>>>(cw1, wt1);
    prep_x<<<(TSTEPS * BATCH * WIDTH + 255) / 256, 256, 0, stream>>>(x, xT);

    dim3 cgrid(BATCH, 8);
    for (int t = 0; t < TSTEPS; ++t) {
        const _Float16* h0r = (t & 1) ? h0b : h0a;
        _Float16*       h0w = (t & 1) ? h0a : h0b;
        const float*    c0r = (t & 1) ? c0b : c0a;
        float*          c0w = (t & 1) ? c0a : c0b;
        const _Float16* h1r = (t & 1) ? h1b : h1a;
        _Float16*       h1w = (t & 1) ? h1a : h1b;
        conv2_step<<<cgrid, 256, 0, stream>>>(
            xT, wt0, wt1, cb0, cb1,
            h0r, h0w, c0r, c0w, h1r, h1w, c1, fcin, t);
    }

    fc1_mfma<<<256, 512, 0, stream>>>(fcin, w1, part);
    fc1_reduce<<<64, 256, 0, stream>>>(part, b1, z1);
    fc2_kernel<<<1, 128, 0, stream>>>(z1, w2, b2, out);
}